// Round 10
// baseline (1454.491 us; speedup 1.0000x reference)
//
#include <hip/hip_runtime.h>
#include <math.h>

#define TT 1024
#define NB 64

typedef float f32x4 __attribute__((ext_vector_type(4)));
typedef __bf16 bf16x8 __attribute__((ext_vector_type(8)));

__device__ __forceinline__ float4 ld4(const float* p){ return *(const float4*)p; }
__device__ __forceinline__ unsigned short bf16rne(float x){
  unsigned u = __float_as_uint(x);
  return (unsigned short)((u + 0x7FFF + ((u >> 16) & 1)) >> 16);
}

// ================= bf16 MFMA GEMM: C = epi(A @ B^T_panels) =================
template<int EPI, int OUTBF>
__global__ __launch_bounds__(256)
void mgemm_k(const unsigned short* __restrict__ A, const unsigned short* __restrict__ B,
             void* __restrict__ Cv, int K, int lda, int ldb, int ldc,
             long sA, long sB, long sC,
             const float* __restrict__ bias,
             const float* __restrict__ e1, long sE1, const float* __restrict__ e2)
{
  const int bz = blockIdx.z;
  A += (long)bz * sA; B += (long)bz * sB;
  __shared__ char lds[16384];
  char* As = lds; char* Bs = lds + 8192;
  const int tid = threadIdx.x;
  const int l = tid & 63, wid = tid >> 6;
  const int wr = wid >> 1, wc = wid & 1;
  const int m0 = blockIdx.y * 128, n0 = blockIdx.x * 128;
  const int lrow = l & 15, lslot = (l >> 4) << 4;
  f32x4 acc[4][4] = {};

  for (int kk = 0; kk < K; kk += 32) {
#pragma unroll
    for (int i = 0; i < 2; ++i) {
      int idx = i * 256 + tid;
      int row = idx >> 2, c16 = (idx & 3) << 4;
      int sw = c16 ^ (((row >> 1) & 3) << 4);
      uint4 va = *(const uint4*)(A + (long)(m0 + row) * lda + kk + (c16 >> 1));
      *(uint4*)(As + row * 64 + sw) = va;
      uint4 vb = *(const uint4*)(B + (long)(n0 + row) * ldb + kk + (c16 >> 1));
      *(uint4*)(Bs + row * 64 + sw) = vb;
    }
    __syncthreads();
    bf16x8 af[4], bfr[4];
#pragma unroll
    for (int t = 0; t < 4; ++t) {
      int ra = wr * 64 + t * 16 + lrow;
      af[t]  = *(const bf16x8*)(As + ra * 64 + (lslot ^ (((ra >> 1) & 3) << 4)));
      int rb = wc * 64 + t * 16 + lrow;
      bfr[t] = *(const bf16x8*)(Bs + rb * 64 + (lslot ^ (((rb >> 1) & 3) << 4)));
    }
#pragma unroll
    for (int mi = 0; mi < 4; ++mi)
#pragma unroll
      for (int ni = 0; ni < 4; ++ni)
        acc[mi][ni] = __builtin_amdgcn_mfma_f32_16x16x32_bf16(af[mi], bfr[ni], acc[mi][ni], 0, 0, 0);
    __syncthreads();
  }

  float* Cf = (float*)Cv; unsigned short* Cb = (unsigned short*)Cv;
  if (OUTBF) Cb += (long)bz * sC; else Cf += (long)bz * sC;
  if (e1) e1 += (long)bz * sE1;
#pragma unroll
  for (int mi = 0; mi < 4; ++mi)
#pragma unroll
  for (int ni = 0; ni < 4; ++ni)
#pragma unroll
  for (int r = 0; r < 4; ++r) {
    int m = m0 + wr * 64 + mi * 16 + ((l >> 4) << 2) + r;
    int n = n0 + wc * 64 + ni * 16 + (l & 15);
    float v = acc[mi][ni][r];
    if (EPI == 1) v = tanhf(v + bias[n]);
    else if (EPI == 2) v = (m == n) ? 0.f : expf(tanhf(v));
    else if (EPI == 3) v = fmaxf(v + bias[n], 0.f);
    else if (EPI == 4) v = v + e1[m] * e2[n];
    if (OUTBF) Cb[(long)m * ldc + n] = bf16rne(v);
    else       Cf[(long)m * ldc + n] = v;
  }
}

// ========== dual-output variant for pinp (z<8) / cinp (z>=8), bf16 out ==========
__global__ __launch_bounds__(256)
void mgemm_pc_k(const unsigned short* __restrict__ A1, const unsigned short* __restrict__ A2,
                const unsigned short* __restrict__ B,
                unsigned short* __restrict__ C1, unsigned short* __restrict__ C2,
                int K, int lda, int ldb, int ldc, long sA, long sB, long sC,
                const float* __restrict__ e1, long sE1, const float* __restrict__ e2)
{
  const int z = blockIdx.z;
  const int bz = z & 7;
  const bool second = (z >= 8);
  const unsigned short* A = (second ? A2 : A1) + (long)bz * sA;
  const unsigned short* Bp = B + (long)bz * sB;
  unsigned short* C = (second ? C2 : C1) + (long)bz * sC;
  const float* e1p = second ? nullptr : (e1 + (long)bz * sE1);
  __shared__ char lds[16384];
  char* As = lds; char* Bs = lds + 8192;
  const int tid = threadIdx.x;
  const int l = tid & 63, wid = tid >> 6;
  const int wr = wid >> 1, wc = wid & 1;
  const int m0 = blockIdx.y * 128, n0 = blockIdx.x * 128;
  const int lrow = l & 15, lslot = (l >> 4) << 4;
  f32x4 acc[4][4] = {};
  for (int kk = 0; kk < K; kk += 32) {
#pragma unroll
    for (int i = 0; i < 2; ++i) {
      int idx = i * 256 + tid;
      int row = idx >> 2, c16 = (idx & 3) << 4;
      int sw = c16 ^ (((row >> 1) & 3) << 4);
      uint4 va = *(const uint4*)(A + (long)(m0 + row) * lda + kk + (c16 >> 1));
      *(uint4*)(As + row * 64 + sw) = va;
      uint4 vb = *(const uint4*)(Bp + (long)(n0 + row) * ldb + kk + (c16 >> 1));
      *(uint4*)(Bs + row * 64 + sw) = vb;
    }
    __syncthreads();
    bf16x8 af[4], bfr[4];
#pragma unroll
    for (int t = 0; t < 4; ++t) {
      int ra = wr * 64 + t * 16 + lrow;
      af[t]  = *(const bf16x8*)(As + ra * 64 + (lslot ^ (((ra >> 1) & 3) << 4)));
      int rb = wc * 64 + t * 16 + lrow;
      bfr[t] = *(const bf16x8*)(Bs + rb * 64 + (lslot ^ (((rb >> 1) & 3) << 4)));
    }
#pragma unroll
    for (int mi = 0; mi < 4; ++mi)
#pragma unroll
      for (int ni = 0; ni < 4; ++ni)
        acc[mi][ni] = __builtin_amdgcn_mfma_f32_16x16x32_bf16(af[mi], bfr[ni], acc[mi][ni], 0, 0, 0);
    __syncthreads();
  }
#pragma unroll
  for (int mi = 0; mi < 4; ++mi)
#pragma unroll
  for (int ni = 0; ni < 4; ++ni)
#pragma unroll
  for (int r = 0; r < 4; ++r) {
    int m = m0 + wr * 64 + mi * 16 + ((l >> 4) << 2) + r;
    int n = n0 + wc * 64 + ni * 16 + (l & 15);
    float v = acc[mi][ni][r];
    if (e1p) v = v + e1p[m] * e2[n];
    C[(long)m * ldc + n] = bf16rne(v);
  }
}

// ---------------- feature split (+ strb bf16 emit) ----------------
__global__ void split_k(const float* __restrict__ in, float* __restrict__ sem,
                        float* __restrict__ str, unsigned short* __restrict__ strb){
  long row = blockIdx.x;
  int c = threadIdx.x << 2;
  float4 v = ld4(in + row * 1024 + c);
  bool isStr = (c >= 256 && c < 512) || (c >= 768);
  int off;
  float* dst;
  if (c < 256)      { dst = sem + row * 512 + c;               off = c; }
  else if (c < 512) { dst = str + row * 512 + (c - 256);       off = c - 256; }
  else if (c < 768) { dst = sem + row * 512 + 256 + (c - 512); off = 0; }
  else              { dst = str + row * 512 + 256 + (c - 768); off = 256 + (c - 768); }
  *(float4*)dst = v;
  if (isStr) {
    unsigned lo = bf16rne(v.x) | ((unsigned)bf16rne(v.y) << 16);
    unsigned hi = bf16rne(v.z) | ((unsigned)bf16rne(v.w) << 16);
    uint2 w; w.x = lo; w.y = hi;
    *(uint2*)(strb + row * 512 + off) = w;
  }
}

// ---------------- fused 3-weight cast ----------------
__global__ void castw3_k(const float* __restrict__ Wtp, const float* __restrict__ Wtc,
                         const float* __restrict__ Wfz,
                         unsigned short* __restrict__ wtpb, unsigned short* __restrict__ wtcb,
                         unsigned short* __restrict__ wfzb){
  long i = ((long)blockIdx.x * 256 + threadIdx.x) << 2;
  const float* src; unsigned short* dst; long off;
  if (i < 262144)      { src = Wtp; dst = wtpb; off = i; }
  else if (i < 524288) { src = Wtc; dst = wtcb; off = i - 262144; }
  else                 { src = Wfz; dst = wfzb; off = i - 524288; }
  float4 v = ld4(src + off);
  unsigned lo = bf16rne(v.x) | ((unsigned)bf16rne(v.y) << 16);
  unsigned hi = bf16rne(v.z) | ((unsigned)bf16rne(v.w) << 16);
  uint2 w; w.x = lo; w.y = hi;
  *(uint2*)(dst + off) = w;
}

__global__ __launch_bounds__(256) void castT_k(const float* __restrict__ src, unsigned short* __restrict__ dst,
                                               int R, int C, long sS, long sD){
  int b = blockIdx.z;
  src += (long)b * sS; dst += (long)b * sD;
  __shared__ float t[32][33];
  int r0 = blockIdx.y * 32, c0 = blockIdx.x * 32;
  int tx = threadIdx.x & 31, ty = threadIdx.x >> 5;
#pragma unroll
  for (int j = 0; j < 32; j += 8)
    t[ty + j][tx] = src[(long)(r0 + ty + j) * C + c0 + tx];
  __syncthreads();
#pragma unroll
  for (int j = 0; j < 32; j += 8)
    dst[(long)(c0 + ty + j) * R + r0 + tx] = bf16rne(t[tx][ty + j]);
}

__global__ void semcopy_k(const float* __restrict__ sem, unsigned short* __restrict__ finpb){
  long idx = ((long)blockIdx.x * 256 + threadIdx.x) << 2;
  long row = idx >> 9; int col = (int)(idx & 511);
  float4 v = ld4(sem + idx);
  unsigned lo = bf16rne(v.x) | ((unsigned)bf16rne(v.y) << 16);
  unsigned hi = bf16rne(v.z) | ((unsigned)bf16rne(v.w) << 16);
  uint2 w; w.x = lo; w.y = hi;
  *(uint2*)(finpb + row * 1536 + col) = w;
}

// ---------------- f_i = exp(tanh(str . wfi)) ----------------
__global__ void fi_k(const float* __restrict__ str, const float* __restrict__ wfi, float* __restrict__ fi){
  int row = blockIdx.x * 4 + (threadIdx.x >> 6);
  int lane = threadIdx.x & 63;
  const float* p = str + (long)row * 512;
  float acc = 0.f;
  for (int c = lane; c < 512; c += 64) acc = fmaf(p[c], wfi[c], acc);
  for (int off = 32; off; off >>= 1) acc += __shfl_down(acc, off, 64);
  if (lane == 0) fi[row] = expf(tanhf(acc));
}

// ---------------- column sums (8 row-chunk partials) ----------------
__global__ void colsum_k(const float* __restrict__ A, float* __restrict__ csp){
  int b = blockIdx.y, rc = blockIdx.z;
  int j = blockIdx.x * 256 + threadIdx.x;
  const float* p = A + (long)b * TT * TT + (long)rc * 128 * TT + j;
  float acc = 0.f;
  for (int i = 0; i < 128; ++i) acc += p[(long)i * TT];
  csp[rc * 8192 + b * TT + j] = acc;
}

// ---------------- build L_bar (+ emit Cold0 hi/lo) ----------------
__global__ void buildw_k(const float* __restrict__ A, const float* __restrict__ fi,
                         const float* __restrict__ csp, float* __restrict__ W,
                         unsigned short* __restrict__ Ch0, unsigned short* __restrict__ Cl0){
  long idx = (long)blockIdx.x * 256 + threadIdx.x;
  long b = idx >> 20;
  long r = idx & 1048575;
  int i = (int)(r >> 10), j = (int)(r & 1023);
  float v;
  if (i == 0)      v = fi[b * TT + j];
  else if (i == j) {
    v = 0.f;
#pragma unroll
    for (int c = 0; c < 8; ++c) v += csp[c * 8192 + b * TT + j];
  }
  else             v = -A[idx];
  W[idx] = v;
  if (j < 64) {
    unsigned short h = bf16rne(v);
    float hf = __uint_as_float((unsigned)h << 16);
    Ch0[b * 65536 + i * 64 + j] = h;
    Cl0[b * 65536 + i * 64 + j] = bf16rne(v - hf);
  }
}

// ---------------- GJ fused: per-block {invert 64x64 diag in LDS} + {Rnew 128-col chunk} ----------------
// grid (8 batches-x, 8 J-chunks-y), 256 thr.
__global__ __launch_bounds__(256) void gj_fprep_k(const float* __restrict__ W,
                                                  float* __restrict__ Rnew,
                                                  unsigned short* __restrict__ RTh, unsigned short* __restrict__ RTl,
                                                  int k0){
  __shared__ float Pa[64][68];
  __shared__ float Pb[64][68];
  __shared__ float S[64][132];
  int b = blockIdx.x;
  int J = blockIdx.y * 128;
  int tid = threadIdx.x;
  int r = tid & 63, q16 = (tid >> 6) << 4;
  const float* Wd = W + (long)b * 1048576 + (long)(k0 + r) * 1024 + k0 + q16;
#pragma unroll
  for (int j = 0; j < 16; j += 4) *(float4*)&Pa[r][q16 + j] = ld4(Wd + j);
  // stage W rows [k0, k0+64) x cols [J, J+128) (independent of GJ)
  const float* Wr = W + (long)b * 1048576 + (long)k0 * 1024 + J;
  for (int i = tid; i < 2048; i += 256) {
    int q = i >> 5, j4 = (i & 31) << 2;
    *(float4*)&S[q][j4] = ld4(Wr + (long)q * 1024 + j4);
  }
  __syncthreads();
#define DSTEP(kv, SRC, DST) { \
    int k_ = (kv); \
    float pk = SRC[k_][k_]; \
    float f  = SRC[r][k_]; \
    float pr = 1.f / pk; \
    bool piv = (r == k_); \
    float t = piv ? -pr : f * pr; \
    float ov[16]; \
    _Pragma("unroll") \
    for (int c = 0; c < 16; ++c) { \
      float pv = SRC[k_][q16 + c]; \
      float z = piv ? 0.f : SRC[r][q16 + c]; \
      float val = fmaf(-t, pv, z); \
      if (q16 + c == k_) val = -t; \
      ov[c] = val; \
    } \
    _Pragma("unroll") \
    for (int j = 0; j < 16; j += 4) *(float4*)&DST[r][q16 + j] = *(float4*)&ov[j]; \
    __syncthreads(); }
  for (int k = 0; k < 64; k += 2) {
    DSTEP(k, Pa, Pb)
    DSTEP(k + 1, Pb, Pa)
  }
  // Pa = Dinv. Transpose into Pb: Pb[q][p] = Dinv[p][q]
  for (int i = tid; i < 4096; i += 256) {
    int q = i >> 6, p = i & 63;
    Pb[q][p] = Pa[p][q];
  }
  __syncthreads();
  // Rnew chunk: out[p][cg+c] = sum_q Dinv[p][q] * S[q][cg+c]
  int p = tid & 63, cg = (tid >> 6) << 5;
  float acc[32] = {};
  for (int q = 0; q < 64; ++q) {
    float d = Pb[q][p];
#pragma unroll
    for (int c = 0; c < 32; ++c) acc[c] = fmaf(d, S[q][cg + c], acc[c]);
  }
  __syncthreads();
#pragma unroll
  for (int c = 0; c < 32; ++c) {
    int jg = J + cg + c;
    float v = acc[c];
    if (jg >= k0 && jg < k0 + 64) v = Pb[jg - k0][p];
    S[p][cg + c] = v;
  }
  __syncthreads();
  float* Rb = Rnew + (long)b * 65536 + J;
  for (int i = tid; i < 2048; i += 256) {
    int rr = i >> 5, j4 = (i & 31) << 2;
    *(float4*)(Rb + (long)rr * 1024 + j4) = *(float4*)&S[rr][j4];
  }
  unsigned short* th = RTh + (long)b * 65536 + (long)J * 64;
  unsigned short* tl = RTl + (long)b * 65536 + (long)J * 64;
  for (int i = tid; i < 8192; i += 256) {
    int jl = i >> 6, pp = i & 63;
    float v = S[pp][jl];
    unsigned short h = bf16rne(v);
    float hf = __uint_as_float((unsigned)h << 16);
    th[i] = h;
    tl[i] = bf16rne(v - hf);
  }
}

// ---------------- GJ trailing update: 64x64 tiles, bf16x3 MFMA, global-direct fragments ----------------
// grid (8 batches-x, 16 mtiles-y, 16 ntiles-z), 256 thr, zero LDS.
__global__ __launch_bounds__(256) void gupd_k(const unsigned short* __restrict__ Ch, const unsigned short* __restrict__ Cl,
                                              const unsigned short* __restrict__ RTh, const unsigned short* __restrict__ RTl,
                                              const float* __restrict__ Rnew, float* __restrict__ W,
                                              unsigned short* __restrict__ ChN, unsigned short* __restrict__ ClN, int k0){
  int b = blockIdx.x;
  const unsigned short* Ahp = Ch + (long)b * 65536;
  const unsigned short* Alp = Cl + (long)b * 65536;
  const unsigned short* Bhp = RTh + (long)b * 65536;
  const unsigned short* Blp = RTl + (long)b * 65536;
  const float* Rb = Rnew + (long)b * 65536;
  float* Wb = W + (long)b * 1048576;
  unsigned short* CnH = ChN + (long)b * 65536;
  unsigned short* CnL = ClN + (long)b * 65536;
  const int tid = threadIdx.x, l = tid & 63, wid = tid >> 6;
  const int wr = wid >> 1, wc = wid & 1;
  const int m0 = blockIdx.y * 64, n0 = blockIdx.z * 64;
  const int lrow = l & 15, kc8 = (l >> 4) << 3;
  f32x4 acc[2][2] = {};
#pragma unroll
  for (int kk = 0; kk < 2; ++kk) {
    bf16x8 ah[2], al4[2], bh[2], bl4[2];
#pragma unroll
    for (int t = 0; t < 2; ++t) {
      int ra = m0 + wr * 32 + t * 16 + lrow;
      long offa = (long)ra * 64 + kk * 32 + kc8;
      ah[t]  = *(const bf16x8*)(Ahp + offa);
      al4[t] = *(const bf16x8*)(Alp + offa);
      int rb = n0 + wc * 32 + t * 16 + lrow;
      long offb = (long)rb * 64 + kk * 32 + kc8;
      bh[t]  = *(const bf16x8*)(Bhp + offb);
      bl4[t] = *(const bf16x8*)(Blp + offb);
    }
#pragma unroll
    for (int mi = 0; mi < 2; ++mi)
#pragma unroll
      for (int ni = 0; ni < 2; ++ni) {
        acc[mi][ni] = __builtin_amdgcn_mfma_f32_16x16x32_bf16(ah[mi],  bh[ni],  acc[mi][ni], 0, 0, 0);
        acc[mi][ni] = __builtin_amdgcn_mfma_f32_16x16x32_bf16(ah[mi],  bl4[ni], acc[mi][ni], 0, 0, 0);
        acc[mi][ni] = __builtin_amdgcn_mfma_f32_16x16x32_bf16(al4[mi], bh[ni],  acc[mi][ni], 0, 0, 0);
      }
  }
#pragma unroll
  for (int mi = 0; mi < 2; ++mi)
#pragma unroll
  for (int ni = 0; ni < 2; ++ni)
#pragma unroll
  for (int r = 0; r < 4; ++r) {
    int m = m0 + wr * 32 + mi * 16 + ((l >> 4) << 2) + r;
    int n = n0 + wc * 32 + ni * 16 + (l & 15);
    bool rowK = (m >= k0 && m < k0 + 64);
    bool colK = (n >= k0 && n < k0 + 64);
    float v;
    if (rowK)      v = Rb[(long)(m - k0) * 1024 + n];
    else if (colK) v = -acc[mi][ni][r];
    else           v = Wb[(long)m * 1024 + n] - acc[mi][ni][r];
    Wb[(long)m * 1024 + n] = v;
    int cn = n - k0 - 64;
    if (cn >= 0 && cn < 64) {
      unsigned short h = bf16rne(v);
      float hf = __uint_as_float((unsigned)h << 16);
      CnH[(long)m * 64 + cn] = h;
      CnL[(long)m * 64 + cn] = bf16rne(v - hf);
    }
  }
}

// ---------------- d0, diag, df col 0 ----------------
__global__ void ddiag_k(const float* __restrict__ W, const float* __restrict__ fi,
                        float* __restrict__ d0, float* __restrict__ diag, float* __restrict__ dfout){
  int t = blockIdx.x * 256 + threadIdx.x;
  int b = t >> 10, i = t & 1023;
  const float* Wb = W + (long)b * TT * TT;
  float dv = fi[t] * Wb[(long)i * TT];
  d0[t] = dv;
  diag[t] = Wb[(long)i * TT + i];
  dfout[(long)b * TT * 1025 + (long)i * 1025] = dv;
}

// ---------------- dx: compute, emit bf16 dx + bf16 dx^T + df store ----------------
__global__ __launch_bounds__(256) void dx_k(const float* __restrict__ A, const float* __restrict__ W,
                                            const float* __restrict__ diag, float* __restrict__ dfout,
                                            unsigned short* __restrict__ dxb, unsigned short* __restrict__ dxTb){
  int b = blockIdx.z;
  int i0 = blockIdx.y * 64, j0 = blockIdx.x * 64;
  const float* Wb = W + (long)b * TT * TT;
  const float* Ab = A + (long)b * TT * TT;
  __shared__ float Ls[64][65];
  __shared__ float Sx[64][65];
  int tid = threadIdx.x;
  for (int idx = tid; idx < 4096; idx += 256) {
    int r = idx >> 6, c = idx & 63;
    Ls[r][c] = Wb[(long)(j0 + r) * TT + i0 + c];
  }
  __syncthreads();
  for (int idx = tid; idx < 4096; idx += 256) {
    int r = idx >> 6, c = idx & 63;
    int i = i0 + r, j = j0 + c;
    float a = Ab[(long)i * TT + j];
    float v = 0.f;
    if (j > 0) v = a * diag[b * TT + j];
    if (i > 0) v -= a * Ls[c][r];
    dxb[(long)b * 1048576 + (long)i * 1024 + j] = bf16rne(v);
    Sx[r][c] = v;
  }
  __syncthreads();
  float* dfb = dfout + (long)b * TT * 1025;
  unsigned short* dtb = dxTb + (long)b * 1048576;
  for (int idx = tid; idx < 4096; idx += 256) {
    int r = idx >> 6, c = idx & 63;
    float v = Sx[c][r];
    dfb[(long)(j0 + r) * 1025 + i0 + 1 + c] = v;
    dtb[(long)(j0 + r) * 1024 + i0 + c] = bf16rne(v);
  }
}

extern "C" void kernel_launch(void* const* d_in, const int* in_sizes, int n_in,
                              void* d_out, int out_size, void* d_ws, size_t ws_size,
                              hipStream_t stream){
  const float* input   = (const float*)d_in[0];
  const float* Wtp     = (const float*)d_in[1];
  const float* btp     = (const float*)d_in[2];
  const float* Wtc     = (const float*)d_in[3];
  const float* btc     = (const float*)d_in[4];
  const float* wfi     = (const float*)d_in[5];
  const float* Wbil    = (const float*)d_in[6];
  const float* exparam = (const float*)d_in[7];
  const float* Wfz     = (const float*)d_in[8];
  const float* bfz     = (const float*)d_in[9];

  if (ws_size < 150000000UL) return;

  float* ws   = (float*)d_ws;
  float* sem   = ws;                    // 4,194,304 f
  float* strv  = ws + 4194304;          // 4,194,304 f  [later: dxb bf16]
  float* Abuf  = ws + 8388608;          // 8,388,608 f  [later: finpb bf16]
  float* Wbuf  = ws + 16777216;         // 8,388,608 f
  unsigned short* strb = (unsigned short*)(ws + 25165824);
  unsigned short* tpb  = (unsigned short*)(ws + 27262976);
  unsigned short* tcb  = (unsigned short*)(ws + 29360128);
  unsigned short* tpwb = (unsigned short*)(ws + 31457280);
  unsigned short* wtpb = (unsigned short*)(ws + 33554432);
  unsigned short* wtcb = (unsigned short*)(ws + 33685504);
  unsigned short* wbilT= (unsigned short*)(ws + 33816576);
  unsigned short* wfzb = (unsigned short*)(ws + 33947648);
  float* fi    = ws + 34340864;         // 8192
  float* csp   = ws + 34349056;         // 65,536
  float* d0    = ws + 34414592;         // 8192
  float* dg    = ws + 34422784;         // 8192
  float* Rnew  = ws + 34463744;         // 524,288
  unsigned short* ChA = (unsigned short*)(ws + 34988032);  // 8x1024x64 bf16
  unsigned short* ClA = (unsigned short*)(ws + 35250176);
  unsigned short* ChB = (unsigned short*)(ws + 35512320);
  unsigned short* ClB = (unsigned short*)(ws + 35774464);
  unsigned short* RTh = (unsigned short*)(ws + 36036608);
  unsigned short* RTl = (unsigned short*)(ws + 36298752);
  unsigned short* dxb   = (unsigned short*)strv;
  unsigned short* dxTb  = (unsigned short*)(ws + 25165824);
  unsigned short* semTb = (unsigned short*)(ws + 29360128);
  unsigned short* finpb = (unsigned short*)Abuf;

  float* outp = (float*)d_out;
  float* dfp  = outp + 4194304;

  split_k<<<8192, 256, 0, stream>>>(input, sem, strv, strb);
  castw3_k<<<1280, 256, 0, stream>>>(Wtp, Wtc, Wfz, wtpb, wtcb, wfzb);
  castT_k<<<dim3(16,16,1), 256, 0, stream>>>(Wbil, wbilT, 512, 512, 0, 0);
  fi_k<<<2048, 256, 0, stream>>>(strv, wfi, fi);
  mgemm_k<1,1><<<dim3(4,64,1),256,0,stream>>>(strb, wtpb, tpb, 512, 512, 512, 512, 0,0,0, btp, nullptr,0,nullptr);
  mgemm_k<1,1><<<dim3(4,64,1),256,0,stream>>>(strb, wtcb, tcb, 512, 512, 512, 512, 0,0,0, btc, nullptr,0,nullptr);
  mgemm_k<0,1><<<dim3(4,64,1),256,0,stream>>>(tpb, wbilT, tpwb, 512, 512, 512, 512, 0,0,0, nullptr, nullptr,0,nullptr);
  mgemm_k<2,0><<<dim3(8,8,8),256,0,stream>>>(tpwb, tcb, Abuf, 512, 512, 512, 1024, 524288,524288,1048576, nullptr, nullptr,0,nullptr);
  castT_k<<<dim3(16,32,8), 256, 0, stream>>>(sem, semTb, 1024, 512, 524288, 524288);
  colsum_k<<<dim3(4,8,8),256,0,stream>>>(Abuf, csp);
  buildw_k<<<32768,256,0,stream>>>(Abuf, fi, csp, Wbuf, ChA, ClA);
  // blocked in-place Gauss-Jordan: {fprep(dinv+Rnew), gupd} x 16, batch-pinned to XCDs
  for (int s = 0; s < 16; ++s) {
    int k0 = s * NB;
    unsigned short* ChI = (s & 1) ? ChB : ChA;
    unsigned short* ClI = (s & 1) ? ClB : ClA;
    unsigned short* ChO = (s & 1) ? ChA : ChB;
    unsigned short* ClO = (s & 1) ? ClA : ClB;
    gj_fprep_k<<<dim3(8,8),256,0,stream>>>(Wbuf, Rnew, RTh, RTl, k0);
    gupd_k<<<dim3(8,16,16),256,0,stream>>>(ChI, ClI, RTh, RTl, Rnew, Wbuf, ChO, ClO, k0);
  }
  ddiag_k<<<32,256,0,stream>>>(Wbuf, fi, d0, dg, dfp);
  dx_k<<<dim3(16,16,8),256,0,stream>>>(Abuf, Wbuf, dg, dfp, dxb, dxTb);
  semcopy_k<<<4096,256,0,stream>>>(sem, finpb);
  mgemm_pc_k<<<dim3(4,8,16),256,0,stream>>>(dxTb, dxb, semTb, finpb + 512, finpb + 1024,
                                            1024, 1024, 1024, 1536, 1048576, 524288, 1572864,
                                            d0, 1024, exparam);
  mgemm_k<3,0><<<dim3(4,64,1),256,0,stream>>>(finpb, wfzb, outp, 1536, 1536, 1536, 512, 0,0,0, bfz, nullptr,0,nullptr);
}